// Round 3
// baseline (13121.156 us; speedup 1.0000x reference)
//
#include <hip/hip_runtime.h>
#include <hip/hip_bf16.h>
#include <math.h>

// Problem constants
#define Bz   32
#define Nn   128
#define Hh   256
#define Dd   256
#define Ff   512
#define Gg   768      // 3*H
#define NT   1024     // 16 waves per block, 1 block per batch
#define NW   16

typedef short v8s __attribute__((ext_vector_type(8)));   // 8 bf16 (4 VGPRs)
typedef float f4  __attribute__((ext_vector_type(4)));   // MFMA C/D

// Workspace layout (float elements)
#define WS_H0    0                           // [B][256]
#define WS_GH0   (WS_H0 + Bz*Hh)             // [B][768]  h0@Wh+bh
#define WS_ZW1   (WS_GH0 + Bz*Gg)            // [B][512]  z@W1c
#define WS_WBIG  (WS_ZW1 + Bz*Ff)            // [80][8][64][4] uint: B-frags Wh(48 tiles)+W1b(32)
#define WS_WBIG2 (WS_WBIG + 80*8*64*4)       // [80][8][64][4] uint: B-frags Wx(48)+W1a(32)
#define WS_TOTAL (WS_WBIG2 + 80*8*64*4)      // ~2.8 MB

// Dynamic LDS layout (bytes)
#define SM_SBF    0           // ushort[8][8][64][8] bf16 states, A-fragment layout (65536 B)
#define SM_P      65536       // float[768]  psum@Wx
#define SM_GX2    68608       // float[768]
#define SM_BASE   71680       // float[512]
#define SM_PSUM   73728       // float[256]
#define SM_HPF    74752       // float[256]
#define SM_H0     75776       // float[256]
#define SM_GH0    76800       // float[768]
#define SM_ROWT   79872       // float[128]
#define SM_LOG    80384       // float[128]
#define SM_AMASK  80896       // uint[128][4]
#define SM_ANCW   82944       // uint[4]
#define SM_LL     82960       // float
#define SMEM_SZ   83072

__device__ __forceinline__ unsigned short f2bf(float x) {
  unsigned u = __float_as_uint(x);
  u = u + 0x7fffu + ((u >> 16) & 1u);   // RNE
  return (unsigned short)(u >> 16);
}
__device__ __forceinline__ unsigned pack2(float e, float o) {
  return (unsigned)f2bf(e) | ((unsigned)f2bf(o) << 16);
}
__device__ __forceinline__ unsigned pkbf(float x, float y) {
  __hip_bfloat162 h = __float22bfloat162_rn(make_float2(x, y));
  union { __hip_bfloat162 h; unsigned u; } c; c.h = h; return c.u;
}
__device__ __forceinline__ float bf2f(unsigned short s) {
  return __uint_as_float(((unsigned)s) << 16);
}
__device__ __forceinline__ float sigm(float x) { return 1.0f / (1.0f + __expf(-x)); }
__device__ __forceinline__ float tanh_fast(float x) { return 2.0f / (1.0f + __expf(-2.0f*x)) - 1.0f; }
__device__ __forceinline__ v8s u4v(uint4 q) { union { uint4 q; v8s v; } c; c.q = q; return c.v; }

// ---------- prep 1: output L, pack all weights into B-fragment layout ----------
__global__ void __launch_bounds__(256) prep_init(
    const int* __restrict__ tg, const float* __restrict__ Wx,
    const float* __restrict__ Wh, const float* __restrict__ W1,
    float* __restrict__ ws, float* __restrict__ out)
{
  const int stride = gridDim.x * blockDim.x;
  const int t0 = blockIdx.x * blockDim.x + threadIdx.x;

  for (int i = t0; i < Bz*Nn*Nn; i += stride) {         // L = tril(targets, -1)
    int col = i & (Nn-1), row = (i >> 7) & (Nn-1);
    out[i] = (col < row) ? (float)tg[i] : 0.0f;
  }
  for (int i = t0; i < Bz; i += stride) out[Bz*Nn*Nn + i] = 0.0f;

  // B-fragment packing: uint (lane l, word jw) = bf16pair W[k][n],W[k+1][n];
  // k = ks*32 + (l>>4)*8 + 2*jw ; n = nt*16 + (l&15)
  unsigned* Wb  = (unsigned*)(ws + WS_WBIG);
  unsigned* Wb2 = (unsigned*)(ws + WS_WBIG2);
  for (int i = t0; i < 80*8*64*4; i += stride) {
    int jw = i & 3, l = (i >> 2) & 63, ks = (i >> 8) & 7, nt = i >> 11;
    int k = ks*32 + (l >> 4)*8 + 2*jw;
    int n16 = l & 15;
    float lo, hi, lo2, hi2;
    if (nt < 48) { int n = nt*16 + n16;
      lo  = Wh[k*Gg + n];      hi  = Wh[(k+1)*Gg + n];
      lo2 = Wx[k*Gg + n];      hi2 = Wx[(k+1)*Gg + n];
    } else { int f = (nt-48)*16 + n16;
      lo  = W1[(Hh+k)*Ff + f]; hi  = W1[(Hh+k+1)*Ff + f];
      lo2 = W1[k*Ff + f];      hi2 = W1[(k+1)*Ff + f];
    }
    Wb[i]  = pack2(lo, hi);
    Wb2[i] = pack2(lo2, hi2);
  }
}

// ---------- prep 2: per-batch h0, gh0 = h0@Wh+bh, zW1 = z@W1c (fp32) ----------
__global__ void __launch_bounds__(256) prep_batch(
    const float* __restrict__ z, const float* __restrict__ Wi,
    const float* __restrict__ bi, const float* __restrict__ Wh,
    const float* __restrict__ bh, const float* __restrict__ W1,
    float* __restrict__ ws)
{
  const int b = blockIdx.x, tid = threadIdx.x;
  __shared__ float zs[Dd], h0s[Hh];
  zs[tid] = z[b*Dd + tid];
  __syncthreads();
  float acc = bi[tid];
  for (int d = 0; d < Dd; ++d) acc = fmaf(zs[d], Wi[d*Hh + tid], acc);
  const float h0 = tanhf(acc);
  h0s[tid] = h0;
  ws[WS_H0 + b*Hh + tid] = h0;
  __syncthreads();
  for (int g = tid; g < Gg; g += 256) {
    float a = bh[g];
    for (int h = 0; h < Hh; ++h) a = fmaf(h0s[h], Wh[h*Gg + g], a);
    ws[WS_GH0 + b*Gg + g] = a;
  }
  for (int f = tid; f < Ff; f += 256) {
    float a = 0.0f;
    for (int d = 0; d < Dd; ++d) a = fmaf(zs[d], W1[(2*Hh + d)*Ff + f], a);
    ws[WS_ZW1 + b*Ff + f] = a;
  }
}

__device__ __forceinline__ void build_mv(const float* __restrict__ vec, int quad, v8s* av)
{
  #pragma unroll
  for (int ks = 0; ks < 8; ++ks) {
    const float4 a = *(const float4*)(vec + ks*32 + quad*8);
    const float4 c = *(const float4*)(vec + ks*32 + quad*8 + 4);
    union { unsigned u[4]; v8s v; } cv;
    cv.u[0] = pkbf(a.x, a.y); cv.u[1] = pkbf(a.z, a.w);
    cv.u[2] = pkbf(c.x, c.y); cv.u[3] = pkbf(c.z, c.w);
    av[ks] = cv.v;
  }
}

// ---------- main: 1 block/batch, 16 waves, all weights persistent in VGPRs ----------
__global__ void __launch_bounds__(NT, 4) decoder_main(
    const int* __restrict__ tg,
    const float* __restrict__ bx, const float* __restrict__ bh,
    const float* __restrict__ b1, const float* __restrict__ W2,
    const float* __restrict__ b2,
    float* __restrict__ ws, float* __restrict__ out)
{
  const int b = blockIdx.x, tid = threadIdx.x;
  const int lane = tid & 63, wv = tid >> 6;
  const int c16 = lane & 15, quad = lane >> 4;

  extern __shared__ char smem[];
  unsigned short* Sbf = (unsigned short*)(smem + SM_SBF);
  float* P    = (float*)(smem + SM_P);
  float* gx2  = (float*)(smem + SM_GX2);
  float* basef= (float*)(smem + SM_BASE);
  float* psum = (float*)(smem + SM_PSUM);
  float* hpf  = (float*)(smem + SM_HPF);
  float* h0s  = (float*)(smem + SM_H0);
  float* gh0s = (float*)(smem + SM_GH0);
  float* rowt = (float*)(smem + SM_ROWT);
  float* logitsf = (float*)(smem + SM_LOG);
  unsigned* amask = (unsigned*)(smem + SM_AMASK);   // [128][4]
  unsigned* ancw  = (unsigned*)(smem + SM_ANCW);
  float* llacc = (float*)(smem + SM_LL);

  const float* __restrict__ h0g  = ws + WS_H0  + b*Hh;
  const float* __restrict__ gh0g = ws + WS_GH0 + b*Gg;
  const float* __restrict__ zW1g = ws + WS_ZW1 + b*Ff;
  const uint4* __restrict__ WB   = (const uint4*)(ws + WS_WBIG);
  const uint4* __restrict__ WB2  = (const uint4*)(ws + WS_WBIG2);

  // ---- persistent B-fragments in registers (320 VGPRs/lane) ----
  uint4 Bwh0[8], Bwh1[8], Bwh2[8];   // Wh r,u,n tiles (cols wv*16..+15 of each gate)
  uint4 Bwl0[8], Bwl1[8];            // W1b tiles (f-cols 32wv..+31)
  uint4 Bxx0[8], Bxx1[8], Bxx2[8];   // Wx r,u,n tiles
  uint4 Bxa0[8], Bxa1[8];            // W1a tiles
  #pragma unroll
  for (int ks = 0; ks < 8; ++ks) {
    Bwh0[ks] = WB [(( 0 + wv   )*8 + ks)*64 + lane];
    Bwh1[ks] = WB [((16 + wv   )*8 + ks)*64 + lane];
    Bwh2[ks] = WB [((32 + wv   )*8 + ks)*64 + lane];
    Bwl0[ks] = WB [((48 + 2*wv )*8 + ks)*64 + lane];
    Bwl1[ks] = WB [((49 + 2*wv )*8 + ks)*64 + lane];
    Bxx0[ks] = WB2[(( 0 + wv   )*8 + ks)*64 + lane];
    Bxx1[ks] = WB2[((16 + wv   )*8 + ks)*64 + lane];
    Bxx2[ks] = WB2[((32 + wv   )*8 + ks)*64 + lane];
    Bxa0[ks] = WB2[((48 + 2*wv )*8 + ks)*64 + lane];
    Bxa1[ks] = WB2[((49 + 2*wv )*8 + ks)*64 + lane];
  }

  // per-lane constants
  const int hC = wv*16 + c16;                 // this lane's GRU h-column
  const int f0 = 32*wv + c16, f1 = f0 + 16;   // this lane's logit f-columns
  const float bhr = bh[hC], bhu = bh[Hh + hC], bhn = bh[2*Hh + hC];
  const float w20 = W2[f0], w21 = W2[f1];
  const float zb0 = zW1g[f0] + b1[f0], zb1v = zW1g[f1] + b1[f1];
  const float b2v = b2[0];
  const int sb_base = (hC >> 5)*512 + ((hC >> 3) & 3)*128 + (hC & 7);

  // ---- LDS init ----
  for (int i = tid; i < 16384; i += NT) ((unsigned*)Sbf)[i] = 0u;
  for (int i = tid; i < Hh; i += NT) { float h = h0g[i]; h0s[i] = h; psum[i] = h; }
  for (int i = tid; i < Gg; i += NT) gh0s[i] = gh0g[i];
  for (int i = tid; i < Nn*4; i += NT) amask[i] = 0u;
  if (tid == 0) *llacc = 0.0f;
  __syncthreads();
  if (tid < Hh) {   // Sbf row 0 = h0
    const int h = tid;
    Sbf[(h >> 5)*512 + ((h >> 3) & 3)*128 + (h & 7)] = f2bf(h0s[h]);
  }
  __syncthreads();

  for (int t = 1; t < Nn; ++t) {
    const float invt  = 1.0f / (float)t;
    const float invt1 = 1.0f / (float)(t + 1);

    // ---- phase 1a: P = psum@Wx (M=1 replicated MFMA, reg-resident Wx) ----
    {
      v8s amv[8]; build_mv(psum, quad, amv);
      f4 c0 = {0,0,0,0}, c1 = {0,0,0,0}, c2 = {0,0,0,0};
      #pragma unroll
      for (int ks = 0; ks < 8; ++ks) {
        c0 = __builtin_amdgcn_mfma_f32_16x16x32_bf16(amv[ks], u4v(Bxx0[ks]), c0, 0, 0, 0);
        c1 = __builtin_amdgcn_mfma_f32_16x16x32_bf16(amv[ks], u4v(Bxx1[ks]), c1, 0, 0, 0);
        c2 = __builtin_amdgcn_mfma_f32_16x16x32_bf16(amv[ks], u4v(Bxx2[ks]), c2, 0, 0, 0);
      }
      if (quad == 0) { P[hC] = c0[0]; P[Hh + hC] = c1[0]; P[2*Hh + hC] = c2[0]; }
    }
    __syncthreads();

    // ---- phase 1b: h_prov (GRU vs h0), Sbf row t, rowt load ----
    if (tid < Hh) {
      const int h = tid;
      const float gxr = P[h]*invt + bx[h];
      const float gxu = P[Hh+h]*invt + bx[Hh+h];
      const float gxn = P[2*Hh+h]*invt + bx[2*Hh+h];
      const float rv = sigm(gxr + gh0s[h]);
      const float uv = sigm(gxu + gh0s[Hh+h]);
      const float nv = tanh_fast(gxn + rv*gh0s[2*Hh+h]);
      const float hp = (1.0f-uv)*nv + uv*h0s[h];
      hpf[h] = hp;
      Sbf[(t >> 4)*4096 + (h >> 5)*512 + ((h >> 3) & 3)*128 + (t & 15)*8 + (h & 7)] = f2bf(hp);
    } else if (tid < Hh + Nn) {
      const int j = tid - Hh;
      rowt[j] = (j < t) ? (float)tg[b*Nn*Nn + t*Nn + j] : 0.0f;
      logitsf[j] = 0.0f;
    } else if (tid < Hh + Nn + 4) {
      ancw[tid - Hh - Nn] = 0u;
    }
    __syncthreads();

    // ---- phase 1c: gx2 = (P + hpf@Wx)*invt1 + bx ; base = hpf@W1a + zW1 + b1 ; anc OR ----
    {
      v8s ah[8]; build_mv(hpf, quad, ah);
      f4 d0 = {0,0,0,0}, d1 = {0,0,0,0}, d2 = {0,0,0,0}, e0 = {0,0,0,0}, e1 = {0,0,0,0};
      #pragma unroll
      for (int ks = 0; ks < 8; ++ks) {
        d0 = __builtin_amdgcn_mfma_f32_16x16x32_bf16(ah[ks], u4v(Bxx0[ks]), d0, 0, 0, 0);
        d1 = __builtin_amdgcn_mfma_f32_16x16x32_bf16(ah[ks], u4v(Bxx1[ks]), d1, 0, 0, 0);
        d2 = __builtin_amdgcn_mfma_f32_16x16x32_bf16(ah[ks], u4v(Bxx2[ks]), d2, 0, 0, 0);
        e0 = __builtin_amdgcn_mfma_f32_16x16x32_bf16(ah[ks], u4v(Bxa0[ks]), e0, 0, 0, 0);
        e1 = __builtin_amdgcn_mfma_f32_16x16x32_bf16(ah[ks], u4v(Bxa1[ks]), e1, 0, 0, 0);
      }
      if (quad == 0) {
        gx2[hC]        = (P[hC]        + d0[0])*invt1 + bx[hC];
        gx2[Hh + hC]   = (P[Hh + hC]   + d1[0])*invt1 + bx[Hh + hC];
        gx2[2*Hh + hC] = (P[2*Hh + hC] + d2[0])*invt1 + bx[2*Hh + hC];
        basef[f0] = e0[0] + zb0;
        basef[f1] = e1[0] + zb1v;
      }
    }
    if (tid < Nn && tid < t && rowt[tid] > 0.5f) {
      atomicOr(&ancw[0], amask[tid*4+0]); atomicOr(&ancw[1], amask[tid*4+1]);
      atomicOr(&ancw[2], amask[tid*4+2]); atomicOr(&ancw[3], amask[tid*4+3]);
    }
    __syncthreads();

    // ---- phase 2: GEMMs over rows 0..t (GRU) / 0..t-1 (logits) ----
    const float gxr2 = gx2[hC], gxu2 = gx2[Hh + hC], gxn2 = gx2[2*Hh + hC];
    const float bs0 = basef[f0], bs1 = basef[f1];
    float csum = 0.0f;
    const int Mtot = (t + 16) >> 4;
    for (int mt = 0; mt < Mtot; ++mt) {
      const int m0 = mt << 4;
      v8s af[8];
      #pragma unroll
      for (int ks = 0; ks < 8; ++ks)
        af[ks] = *(const v8s*)(Sbf + (mt*8 + ks)*512 + lane*8);
      __syncthreads();   // all A-reads of tile mt done before its epilogue writes

      f4 cr = {0,0,0,0}, cu = {0,0,0,0}, cn = {0,0,0,0};
      #pragma unroll
      for (int ks = 0; ks < 8; ++ks) {
        cr = __builtin_amdgcn_mfma_f32_16x16x32_bf16(af[ks], u4v(Bwh0[ks]), cr, 0, 0, 0);
        cu = __builtin_amdgcn_mfma_f32_16x16x32_bf16(af[ks], u4v(Bwh1[ks]), cu, 0, 0, 0);
        cn = __builtin_amdgcn_mfma_f32_16x16x32_bf16(af[ks], u4v(Bwh2[ks]), cn, 0, 0, 0);
      }
      const bool doLog = (m0 < t);
      f4 cl0 = {0,0,0,0}, cl1 = {0,0,0,0};
      if (doLog) {
        #pragma unroll
        for (int ks = 0; ks < 8; ++ks) {
          cl0 = __builtin_amdgcn_mfma_f32_16x16x32_bf16(af[ks], u4v(Bwl0[ks]), cl0, 0, 0, 0);
          cl1 = __builtin_amdgcn_mfma_f32_16x16x32_bf16(af[ks], u4v(Bwl1[ks]), cl1, 0, 0, 0);
        }
      }

      // GRU epilogue: rows m0+quad*4+rg, col hC (scattered b16 in Sbf)
      #pragma unroll
      for (int rg = 0; rg < 4; ++rg) {
        const int row = m0 + quad*4 + rg;
        if (row <= t) {
          const int sp = mt*4096 + sb_base + (quad*4 + rg)*8;
          const float old = bf2f(Sbf[sp]);
          const float rv = sigm(gxr2 + cr[rg] + bhr);
          const float uv = sigm(gxu2 + cu[rg] + bhu);
          const float nv = tanh_fast(gxn2 + rv*(cn[rg] + bhn));
          const float ns = (1.0f-uv)*nv + uv*old;
          Sbf[sp] = f2bf(ns);
          csum += ns;
        }
      }
      // logits epilogue
      if (doLog) {
        #pragma unroll
        for (int rg = 0; rg < 4; ++rg) {
          float v = fmaxf(cl0[rg] + bs0, 0.0f)*w20 + fmaxf(cl1[rg] + bs1, 0.0f)*w21;
          v += __shfl_xor(v, 1); v += __shfl_xor(v, 2);
          v += __shfl_xor(v, 4); v += __shfl_xor(v, 8);
          const int row = m0 + quad*4 + rg;
          if (c16 == 0 && row < t) atomicAdd(&logitsf[row], v);
        }
      }
    }
    __syncthreads();

    // ---- phase 3: next psum, log-likelihood, ancestor row t ----
    {
      float v = csum;
      v += __shfl_down(v, 16); v += __shfl_down(v, 32);
      if (lane < 16) psum[wv*16 + lane] = v;
    }
    float term = 0.0f;
    if (tid < t) {
      const float anc = (float)((ancw[tid >> 5] >> (tid & 31)) & 1u);
      float q = sigm(logitsf[tid] + b2v) * (1.0f - 0.5f*anc);
      q = fminf(fmaxf(q, 1e-6f), 1.0f - 1e-6f);
      term = rowt[tid]*logf(q) + (1.0f - rowt[tid])*log1pf(-q);
    }
    if (wv < 2) {
      #pragma unroll
      for (int off = 32; off; off >>= 1) term += __shfl_down(term, off);
      if (lane == 0) atomicAdd(llacc, term);
      const unsigned long long bal = __ballot(tid < t && rowt[tid] > 0.5f);
      if (lane == 0) {
        amask[t*4 + 2*wv]     = (unsigned)bal         | ancw[2*wv];
        amask[t*4 + 2*wv + 1] = (unsigned)(bal >> 32) | ancw[2*wv + 1];
      }
    }
    __syncthreads();
  }

  if (tid == 0) out[Bz*Nn*Nn + b] = *llacc;
}

extern "C" void kernel_launch(void* const* d_in, const int* in_sizes, int n_in,
                              void* d_out, int out_size, void* d_ws, size_t ws_size,
                              hipStream_t stream)
{
  const float* z  = (const float*)d_in[0];
  const int*   tg = (const int*)  d_in[1];
  const float* Wi = (const float*)d_in[2];
  const float* bi = (const float*)d_in[3];
  const float* Wx = (const float*)d_in[4];
  const float* Wh = (const float*)d_in[5];
  const float* bx = (const float*)d_in[6];
  const float* bh = (const float*)d_in[7];
  const float* W1 = (const float*)d_in[8];
  const float* b1 = (const float*)d_in[9];
  const float* W2 = (const float*)d_in[10];
  const float* b2 = (const float*)d_in[11];
  float* out = (float*)d_out;
  float* ws  = (float*)d_ws;

  hipFuncSetAttribute((const void*)decoder_main,
                      hipFuncAttributeMaxDynamicSharedMemorySize, SMEM_SZ);

  hipLaunchKernelGGL(prep_init, dim3(512), dim3(256), 0, stream, tg, Wx, Wh, W1, ws, out);
  hipLaunchKernelGGL(prep_batch, dim3(Bz), dim3(256), 0, stream, z, Wi, bi, Wh, bh, W1, ws);
  hipLaunchKernelGGL(decoder_main, dim3(Bz), dim3(NT), SMEM_SZ, stream,
                     tg, bx, bh, b1, W2, b2, ws, out);
}

// Round 4
// 11738.993 us; speedup vs baseline: 1.1177x; 1.1177x over previous
//
#include <hip/hip_runtime.h>
#include <hip/hip_bf16.h>
#include <math.h>

// Problem constants
#define Bz 32
#define Nn 128
#define Hh 256
#define Dd 256
#define Ff 512
#define Gg 768
#define NT 512          // 8 waves per block, 1 block per batch

typedef short v8s __attribute__((ext_vector_type(8)));   // 8 bf16 (4 VGPRs)
typedef float f4  __attribute__((ext_vector_type(4)));   // MFMA C/D

#define MFMA(a, b, c) __builtin_amdgcn_mfma_f32_16x16x32_bf16(a, b, c, 0, 0, 0)

// Workspace layout (float elements)
#define WS_H0    0                         // [B][256]
#define WS_GH0   (WS_H0 + Bz*Hh)           // [B][768]  h0@Wh+bh
#define WS_ZW1   (WS_GH0 + Bz*Gg)          // [B][512]  z@W1c
#define WS_WB    (WS_ZW1 + Bz*Ff)          // [160][8][64][4] uint B-frags:
                                           //   [0,48) Wh | [48,80) W1b | [80,128) Wx | [128,160) W1a
#define WS_TOTAL (WS_WB + 160*8*64*4)

// Dynamic LDS layout (bytes)
#define SM_SB0   0          // ushort[8][8][64][8]  state buffer 0 (A-frag layout)
#define SM_SB1   65536      // state buffer 1
#define SM_PW    131072     // float[768]  psum@Wx
#define SM_PSUM  134144     // float[256]
#define SM_PSN   135168     // float[256]
#define SM_HPF   136192     // float[256]
#define SM_V2    137216     // float[256]  psum+hpf
#define SM_H0S   138240     // float[256]
#define SM_GH0S  139264     // float[768]
#define SM_BXS   142336     // float[768]
#define SM_ZB1   145408     // float[512]  zW1 + b1
#define SM_ROWT  147456     // float[128]
#define SM_LOGI  147968     // float[128]
#define SM_AMASK 148480     // uint[128][4]
#define SM_ANCW  150528     // uint[4]
#define SM_LL    150544     // float
#define SMEM_SZ  150592

__device__ __forceinline__ unsigned short f2bf(float x) {
  unsigned u = __float_as_uint(x);
  u = u + 0x7fffu + ((u >> 16) & 1u);   // RNE
  return (unsigned short)(u >> 16);
}
__device__ __forceinline__ unsigned pack2(float e, float o) {
  return (unsigned)f2bf(e) | ((unsigned)f2bf(o) << 16);
}
__device__ __forceinline__ unsigned pkbf(float x, float y) {
  __hip_bfloat162 h = __float22bfloat162_rn(make_float2(x, y));
  union { __hip_bfloat162 h; unsigned u; } c; c.h = h; return c.u;
}
__device__ __forceinline__ float bf2f(unsigned short s) {
  return __uint_as_float(((unsigned)s) << 16);
}
__device__ __forceinline__ float sigm(float x) { return 1.0f / (1.0f + __expf(-x)); }
__device__ __forceinline__ float tanh_fast(float x) { return 2.0f / (1.0f + __expf(-2.0f*x)) - 1.0f; }
__device__ __forceinline__ v8s u4v(uint4 q) { union { uint4 q; v8s v; } c; c.q = q; return c.v; }

// Build M=1-replicated A-fragments from an fp32 vector in LDS (all 16 rows = vec)
__device__ __forceinline__ void build_mv(const float* __restrict__ vec, int quad, v8s* av)
{
  #pragma unroll
  for (int ks = 0; ks < 8; ++ks) {
    const float4 a = *(const float4*)(vec + ks*32 + quad*8);
    const float4 c = *(const float4*)(vec + ks*32 + quad*8 + 4);
    union { unsigned u[4]; v8s v; } cv;
    cv.u[0] = pkbf(a.x, a.y); cv.u[1] = pkbf(a.z, a.w);
    cv.u[2] = pkbf(c.x, c.y); cv.u[3] = pkbf(c.z, c.w);
    av[ks] = cv.v;
  }
}

// ---------- prep 1: output L, pack all weights into B-fragment stream ----------
__global__ void __launch_bounds__(256) prep_init(
    const int* __restrict__ tg, const float* __restrict__ Wx,
    const float* __restrict__ Wh, const float* __restrict__ W1,
    float* __restrict__ ws, float* __restrict__ out)
{
  const int stride = gridDim.x * blockDim.x;
  const int t0 = blockIdx.x * blockDim.x + threadIdx.x;

  for (int i = t0; i < Bz*Nn*Nn; i += stride) {         // L = tril(targets, -1)
    int col = i & (Nn-1), row = (i >> 7) & (Nn-1);
    out[i] = (col < row) ? (float)tg[i] : 0.0f;
  }
  for (int i = t0; i < Bz; i += stride) out[Bz*Nn*Nn + i] = 0.0f;

  // B-frag packing: uint (lane l, word jw) = bf16pair W[k][n],W[k+1][n];
  // k = ks*32 + (l>>4)*8 + 2*jw ; n = tile_local*16 + (l&15)
  unsigned* Wb = (unsigned*)(ws + WS_WB);
  for (int i = t0; i < 160*2048; i += stride) {
    int jw = i & 3, l = (i >> 2) & 63, ks = (i >> 8) & 7, nt = i >> 11;
    int k = ks*32 + (l >> 4)*8 + 2*jw;
    int n16 = l & 15;
    float lo, hi;
    if (nt < 48)       { int c = nt*16 + n16;        lo = Wh[k*Gg + c];      hi = Wh[(k+1)*Gg + c]; }
    else if (nt < 80)  { int f = (nt-48)*16 + n16;   lo = W1[(Hh+k)*Ff + f]; hi = W1[(Hh+k+1)*Ff + f]; }
    else if (nt < 128) { int c = (nt-80)*16 + n16;   lo = Wx[k*Gg + c];      hi = Wx[(k+1)*Gg + c]; }
    else               { int f = (nt-128)*16 + n16;  lo = W1[k*Ff + f];      hi = W1[(k+1)*Ff + f]; }
    Wb[i] = pack2(lo, hi);
  }
}

// ---------- prep 2: per-batch h0, gh0 = h0@Wh+bh, zW1 = z@W1c (fp32) ----------
__global__ void __launch_bounds__(256) prep_batch(
    const float* __restrict__ z, const float* __restrict__ Wi,
    const float* __restrict__ bi, const float* __restrict__ Wh,
    const float* __restrict__ bh, const float* __restrict__ W1,
    float* __restrict__ ws)
{
  const int b = blockIdx.x, tid = threadIdx.x;
  __shared__ float zs[Dd], h0s[Hh];
  zs[tid] = z[b*Dd + tid];
  __syncthreads();
  float acc = bi[tid];
  for (int d = 0; d < Dd; ++d) acc = fmaf(zs[d], Wi[d*Hh + tid], acc);
  const float h0 = tanhf(acc);
  h0s[tid] = h0;
  ws[WS_H0 + b*Hh + tid] = h0;
  __syncthreads();
  for (int g = tid; g < Gg; g += 256) {
    float a = bh[g];
    for (int h = 0; h < Hh; ++h) a = fmaf(h0s[h], Wh[h*Gg + g], a);
    ws[WS_GH0 + b*Gg + g] = a;
  }
  for (int f = tid; f < Ff; f += 256) {
    float a = 0.0f;
    for (int d = 0; d < Dd; ++d) a = fmaf(zs[d], W1[(2*Hh + d)*Ff + f], a);
    ws[WS_ZW1 + b*Ff + f] = a;
  }
}

// ---------- main: 1 block/batch, 8 waves, weights streamed from L2 once/use ----------
__global__ void __launch_bounds__(NT, 2) decoder_main(
    const int* __restrict__ tg,
    const float* __restrict__ bx, const float* __restrict__ bh,
    const float* __restrict__ b1, const float* __restrict__ W2,
    const float* __restrict__ b2,
    float* __restrict__ ws, float* __restrict__ out)
{
  const int b = blockIdx.x, tid = threadIdx.x;
  const int lane = tid & 63, wv = tid >> 6;
  const int c16 = lane & 15, quad = lane >> 4;

  extern __shared__ char smem[];
  unsigned short* SB0 = (unsigned short*)(smem + SM_SB0);
  unsigned short* SB1 = (unsigned short*)(smem + SM_SB1);
  float* PW    = (float*)(smem + SM_PW);
  float* PSUMf = (float*)(smem + SM_PSUM);
  float* PSNf  = (float*)(smem + SM_PSN);
  float* HPFf  = (float*)(smem + SM_HPF);
  float* V2f   = (float*)(smem + SM_V2);
  float* H0Sf  = (float*)(smem + SM_H0S);
  float* GH0Sf = (float*)(smem + SM_GH0S);
  float* BXSf  = (float*)(smem + SM_BXS);
  float* ZB1f  = (float*)(smem + SM_ZB1);
  float* ROWTf = (float*)(smem + SM_ROWT);
  float* LOGIf = (float*)(smem + SM_LOGI);
  unsigned* AMASKu = (unsigned*)(smem + SM_AMASK);
  unsigned* ANCWu  = (unsigned*)(smem + SM_ANCW);
  float* LLp = (float*)(smem + SM_LL);

  const float* __restrict__ h0g  = ws + WS_H0  + b*Hh;
  const float* __restrict__ gh0g = ws + WS_GH0 + b*Gg;
  const float* __restrict__ zW1g = ws + WS_ZW1 + b*Ff;
  const uint4* __restrict__ WB   = (const uint4*)(ws + WS_WB);

  // ---- prologue: LDS init ----
  for (int i = tid; i < 32768; i += NT) ((unsigned*)smem)[i] = 0u;   // both S buffers
  for (int i = tid; i < Hh; i += NT) { float h = h0g[i]; H0Sf[i] = h; PSUMf[i] = h; }
  for (int i = tid; i < Gg; i += NT) { GH0Sf[i] = gh0g[i]; BXSf[i] = bx[i]; }
  for (int i = tid; i < Ff; i += NT) ZB1f[i] = zW1g[i] + b1[i];
  for (int i = tid; i < Nn*4; i += NT) AMASKu[i] = 0u;
  if (tid < 4) ANCWu[tid] = 0u;
  if (tid == 4) *LLp = 0.0f;
  __syncthreads();
  if (tid < Hh)   // SB1 row 0 = h0 (step t=1 reads buffer 1)
    SB1[(tid >> 5)*512 + ((tid >> 3) & 3)*128 + (tid & 7)] = f2bf(H0Sf[tid]);

  // per-lane constants
  const int hc0 = 32*wv + c16, hc1 = hc0 + 16;
  const float bhr0 = bh[hc0], bhu0 = bh[Hh+hc0], bhn0 = bh[2*Hh+hc0];
  const float bhr1 = bh[hc1], bhu1 = bh[Hh+hc1], bhn1 = bh[2*Hh+hc1];
  float w2r[4];
  #pragma unroll
  for (int ft = 0; ft < 4; ++ft) w2r[ft] = W2[64*wv + 16*ft + c16];
  const float b2v = b2[0];
  __syncthreads();

  for (int t = 1; t < Nn; ++t) {
    const int p = t & 1;
    unsigned short* SBp = p ? SB1 : SB0;   // read buffer (old states)
    unsigned short* SBn = p ? SB0 : SB1;   // write buffer (new states)
    const float invt  = 1.0f / (float)t;
    const float invt1 = 1.0f / (float)(t + 1);

    // ---- phase 1a: PW = psum@Wx via M=1 MFMA (streams Wx region) ----
    {
      v8s aps[8]; build_mv(PSUMf, quad, aps);
      #pragma unroll
      for (int i = 0; i < 6; ++i) {
        const int tile = 80 + 6*wv + i;
        const uint4* Bp = WB + (tile*8)*64 + lane;
        f4 c = {0.0f, 0.0f, 0.0f, 0.0f};
        #pragma unroll
        for (int ks = 0; ks < 8; ++ks) c = MFMA(aps[ks], u4v(Bp[ks*64]), c);
        if (quad == 0) PW[(6*wv + i)*16 + c16] = c[0];
      }
    }
    __syncthreads();

    // ---- phase 1b: h_prov, row-t write, rowt load, scratch zero ----
    if (tid < Hh) {
      const float gxr = PW[tid]*invt        + BXSf[tid];
      const float gxu = PW[Hh+tid]*invt     + BXSf[Hh+tid];
      const float gxn = PW[2*Hh+tid]*invt   + BXSf[2*Hh+tid];
      const float rv = sigm(gxr + GH0Sf[tid]);
      const float uv = sigm(gxu + GH0Sf[Hh+tid]);
      const float nv = tanh_fast(gxn + rv*GH0Sf[2*Hh+tid]);
      const float hp = (1.0f-uv)*nv + uv*H0Sf[tid];
      HPFf[tid] = hp;
      V2f[tid]  = PSUMf[tid] + hp;
      SBp[((t>>4)*8 + (tid>>5))*512 + ((t&15) + ((tid>>3)&3)*16)*8 + (tid&7)] = f2bf(hp);
    } else if (tid < Hh + Nn) {
      const int j = tid - Hh;
      ROWTf[j] = (j < t) ? (float)tg[b*Nn*Nn + t*Nn + j] : 0.0f;
    } else {
      LOGIf[tid - 384] = 0.0f;
      if (tid >= 508) ANCWu[tid - 508] = 0u;
    }
    __syncthreads();

    // ---- phase 2: matvec slices (register results) + main GEMMs ----
    // ancestor OR (threads 0..127)
    if (tid < Nn && tid < t && ROWTf[tid] > 0.5f) {
      atomicOr(&ANCWu[0], AMASKu[tid*4+0]); atomicOr(&ANCWu[1], AMASKu[tid*4+1]);
      atomicOr(&ANCWu[2], AMASKu[tid*4+2]); atomicOr(&ANCWu[3], AMASKu[tid*4+3]);
    }

    float gxv[6];   // (tt,gate): r0,u0,n0,r1,u1,n1  for this lane's cols hc0/hc1
    {
      v8s av2[8]; build_mv(V2f, quad, av2);
      #pragma unroll
      for (int g = 0; g < 6; ++g) {
        const int tt = g / 3, gate = g % 3;
        const int tile = 80 + gate*16 + 2*wv + tt;
        const uint4* Bp = WB + (tile*8)*64 + lane;
        f4 c = {0.0f, 0.0f, 0.0f, 0.0f};
        #pragma unroll
        for (int ks = 0; ks < 8; ++ks) c = MFMA(av2[ks], u4v(Bp[ks*64]), c);
        const int col = gate*Hh + 32*wv + 16*tt + c16;
        gxv[g] = c[0]*invt1 + BXSf[col];
      }
    }
    float bs[4];
    {
      v8s ahp[8]; build_mv(HPFf, quad, ahp);
      #pragma unroll
      for (int ft = 0; ft < 4; ++ft) {
        const int tile = 128 + 4*wv + ft;
        const uint4* Bp = WB + (tile*8)*64 + lane;
        f4 c = {0.0f, 0.0f, 0.0f, 0.0f};
        #pragma unroll
        for (int ks = 0; ks < 8; ++ks) c = MFMA(ahp[ks], u4v(Bp[ks*64]), c);
        bs[ft] = c[0] + ZB1f[64*wv + 16*ft + c16];
      }
    }

    const int Mtot = (t + 16) >> 4;    // GRU rows 0..t
    const int Mlog = (t + 15) >> 4;    // logit rows 0..t-1

    // GRU jobs: 2 h-tiles, B-frags (Wh triple) register-resident across M-loop
    #pragma unroll
    for (int tt = 0; tt < 2; ++tt) {
      const int ht = 2*wv + tt;
      uint4 br[8], bu[8], bn[8];
      #pragma unroll
      for (int ks = 0; ks < 8; ++ks) {
        br[ks] = WB[((ht     )*8 + ks)*64 + lane];
        bu[ks] = WB[((ht + 16)*8 + ks)*64 + lane];
        bn[ks] = WB[((ht + 32)*8 + ks)*64 + lane];
      }
      const int hc = tt ? hc1 : hc0;
      const float gxr = gxv[tt*3], gxu = gxv[tt*3+1], gxn = gxv[tt*3+2];
      const float bhr = tt ? bhr1 : bhr0;
      const float bhu = tt ? bhu1 : bhu0;
      const float bhn = tt ? bhn1 : bhn0;
      const int spb = (hc >> 5)*512 + ((hc >> 3) & 3)*128 + (hc & 7);
      float colsum = 0.0f;
      for (int mt = 0; mt < Mtot; ++mt) {
        v8s af[8];
        #pragma unroll
        for (int ks = 0; ks < 8; ++ks)
          af[ks] = *(const v8s*)(SBp + (mt*8 + ks)*512 + lane*8);
        f4 cr = {0.0f,0.0f,0.0f,0.0f}, cu = {0.0f,0.0f,0.0f,0.0f}, cn = {0.0f,0.0f,0.0f,0.0f};
        #pragma unroll
        for (int ks = 0; ks < 8; ++ks) {
          cr = MFMA(af[ks], u4v(br[ks]), cr);
          cu = MFMA(af[ks], u4v(bu[ks]), cu);
          cn = MFMA(af[ks], u4v(bn[ks]), cn);
        }
        #pragma unroll
        for (int rg = 0; rg < 4; ++rg) {
          const int row = mt*16 + quad*4 + rg;
          if (row <= t) {
            const int sp = mt*4096 + spb + (quad*4 + rg)*8;
            const float old = bf2f(SBp[sp]);
            const float rv = sigm(gxr + cr[rg] + bhr);
            const float uv = sigm(gxu + cu[rg] + bhu);
            const float nv = tanh_fast(gxn + rv*(cn[rg] + bhn));
            const float ns = (1.0f-uv)*nv + uv*old;
            SBn[sp] = f2bf(ns);
            colsum += ns;
          }
        }
      }
      colsum += __shfl_down(colsum, 16);
      colsum += __shfl_down(colsum, 32);
      if (lane < 16) PSNf[32*wv + 16*tt + lane] = colsum;
    }

    // Logit job: 4 W1b tiles register-resident
    {
      uint4 bl[4][8];
      #pragma unroll
      for (int ft = 0; ft < 4; ++ft)
        #pragma unroll
        for (int ks = 0; ks < 8; ++ks)
          bl[ft][ks] = WB[((48 + 4*wv + ft)*8 + ks)*64 + lane];
      for (int mt = 0; mt < Mlog; ++mt) {
        v8s af[8];
        #pragma unroll
        for (int ks = 0; ks < 8; ++ks)
          af[ks] = *(const v8s*)(SBp + (mt*8 + ks)*512 + lane*8);
        f4 cl0 = {0.0f,0.0f,0.0f,0.0f}, cl1 = {0.0f,0.0f,0.0f,0.0f};
        f4 cl2 = {0.0f,0.0f,0.0f,0.0f}, cl3 = {0.0f,0.0f,0.0f,0.0f};
        #pragma unroll
        for (int ks = 0; ks < 8; ++ks) {
          cl0 = MFMA(af[ks], u4v(bl[0][ks]), cl0);
          cl1 = MFMA(af[ks], u4v(bl[1][ks]), cl1);
          cl2 = MFMA(af[ks], u4v(bl[2][ks]), cl2);
          cl3 = MFMA(af[ks], u4v(bl[3][ks]), cl3);
        }
        #pragma unroll
        for (int rg = 0; rg < 4; ++rg) {
          float v = fmaxf(cl0[rg] + bs[0], 0.0f)*w2r[0]
                  + fmaxf(cl1[rg] + bs[1], 0.0f)*w2r[1]
                  + fmaxf(cl2[rg] + bs[2], 0.0f)*w2r[2]
                  + fmaxf(cl3[rg] + bs[3], 0.0f)*w2r[3];
          v += __shfl_xor(v, 1); v += __shfl_xor(v, 2);
          v += __shfl_xor(v, 4); v += __shfl_xor(v, 8);
          const int row = mt*16 + quad*4 + rg;
          if (c16 == 0 && row < t) atomicAdd(&LOGIf[row], v);
        }
      }
    }
    __syncthreads();

    // ---- phase 3: log-likelihood, ancestor row t, psum swap ----
    float term = 0.0f;
    if (tid < t) {
      const float anc = (float)((ANCWu[tid >> 5] >> (tid & 31)) & 1u);
      float q = sigm(LOGIf[tid] + b2v) * (1.0f - 0.5f*anc);
      q = fminf(fmaxf(q, 1e-6f), 1.0f - 1e-6f);
      term = ROWTf[tid]*logf(q) + (1.0f - ROWTf[tid])*log1pf(-q);
    }
    if (wv < 2) {
      #pragma unroll
      for (int off = 32; off; off >>= 1) term += __shfl_down(term, off);
      if (lane == 0) atomicAdd(LLp, term);
      const unsigned long long bal = __ballot(tid < t && ROWTf[tid] > 0.5f);
      if (lane == 0) {
        AMASKu[t*4 + 2*wv]     = (unsigned)bal         | ANCWu[2*wv];
        AMASKu[t*4 + 2*wv + 1] = (unsigned)(bal >> 32) | ANCWu[2*wv + 1];
      }
    }
    if (tid < Hh) PSUMf[tid] = PSNf[tid];
    __syncthreads();
  }

  if (tid == 0) out[Bz*Nn*Nn + b] = *LLp;
}

extern "C" void kernel_launch(void* const* d_in, const int* in_sizes, int n_in,
                              void* d_out, int out_size, void* d_ws, size_t ws_size,
                              hipStream_t stream)
{
  const float* z  = (const float*)d_in[0];
  const int*   tg = (const int*)  d_in[1];
  const float* Wi = (const float*)d_in[2];
  const float* bi = (const float*)d_in[3];
  const float* Wx = (const float*)d_in[4];
  const float* Wh = (const float*)d_in[5];
  const float* bx = (const float*)d_in[6];
  const float* bh = (const float*)d_in[7];
  const float* W1 = (const float*)d_in[8];
  const float* b1 = (const float*)d_in[9];
  const float* W2 = (const float*)d_in[10];
  const float* b2 = (const float*)d_in[11];
  float* out = (float*)d_out;
  float* ws  = (float*)d_ws;

  hipFuncSetAttribute((const void*)decoder_main,
                      hipFuncAttributeMaxDynamicSharedMemorySize, SMEM_SZ);

  hipLaunchKernelGGL(prep_init, dim3(512), dim3(256), 0, stream, tg, Wx, Wh, W1, ws, out);
  hipLaunchKernelGGL(prep_batch, dim3(Bz), dim3(256), 0, stream, z, Wi, bi, Wh, bh, W1, ws);
  hipLaunchKernelGGL(decoder_main, dim3(Bz), dim3(NT), SMEM_SZ, stream,
                     tg, bx, bh, b1, W2, b2, ws, out);
}

// Round 5
// 5466.913 us; speedup vs baseline: 2.4001x; 2.1473x over previous
//
#include <hip/hip_runtime.h>
#include <hip/hip_bf16.h>
#include <math.h>

// Problem constants
#define Bz 32
#define Nn 128
#define Hh 256
#define Dd 256
#define Ff 512
#define Gg 768
#define NT 512          // 8 waves per block; 256 blocks = 32 batches x 8 col-slices

typedef short v8s __attribute__((ext_vector_type(8)));   // 8 bf16
typedef float f4  __attribute__((ext_vector_type(4)));   // MFMA C/D
#define MFMA(a,b,c) __builtin_amdgcn_mfma_f32_16x16x32_bf16(a,b,c,0,0,0)

// Workspace layout (float elements)
#define WS_H0    0                          // [B][256]
#define WS_GH0   (WS_H0 + Bz*Hh)            // [B][768]
#define WS_ZW1   (WS_GH0 + Bz*Gg)           // [B][512]
#define WS_XH    (WS_ZW1 + Bz*Ff)           // [B][256]   h_prov exchange
#define WS_PSX   (WS_XH + Bz*Hh)            // [B][256]   psum exchange
#define WS_LOGP  (WS_PSX + Bz*Hh)           // [B][8][128] logit partials
#define WS_AMG   (WS_LOGP + Bz*8*Nn)        // [B][128][4] uint ancestor rows
#define WS_BAR   (WS_AMG + Bz*Nn*4)         // [B][32] uint barrier counters (padded)
#define WS_XS    (WS_BAR + Bz*32)           // [B][8mt][8ks][512] ushort state exchange (64KB/b)
#define WS_WB    (WS_XS + Bz*16384)         // [160][8][64][4] uint B-frag packed weights
#define WS_TOTAL (WS_WB + 160*2048)         // ~3.9 MB

// LDS layout (bytes)
#define SM_SW    0         // [10 lt][8 ks][64 lane] uint4 : 6 Wh-tiles + 4 W1b-tiles (81920)
#define SM_SST   81920     // ushort[8mt][8ks][512] bf16 state mirror (65536)
#define SM_NLDS  147456    // ushort[8mt][512] new-state slice staging (8192)
#define SM_PS    155648    // float[256]
#define SM_HPF   156672    // float[256]
#define SM_GX1   157696    // float[96]
#define SM_GX2   158080    // float[96]
#define SM_BASE  158464    // float[64]
#define SM_BXS   158720    // float[96]
#define SM_BHS   159104    // float[96]
#define SM_GH0S  159488    // float[96]
#define SM_ZB1S  159872    // float[64]
#define SM_H0S   160128    // float[32]
#define SM_PSN   160256    // float[32]
#define SM_LOGI  160384    // float[128]
#define SM_ROWT  160896    // float[128]
#define SM_ANCW  161408    // uint[4]
#define SM_LL    161424    // float
#define SMEM_SZ  161440

__device__ __forceinline__ unsigned short f2bf(float x) {
  unsigned u = __float_as_uint(x);
  u = u + 0x7fffu + ((u >> 16) & 1u);   // RNE
  return (unsigned short)(u >> 16);
}
__device__ __forceinline__ unsigned pack2(float e, float o) {
  return (unsigned)f2bf(e) | ((unsigned)f2bf(o) << 16);
}
__device__ __forceinline__ float bf2f(unsigned short s) {
  return __uint_as_float(((unsigned)s) << 16);
}
__device__ __forceinline__ float sigm(float x) { return 1.0f / (1.0f + __expf(-x)); }
__device__ __forceinline__ float tanh_fast(float x) { return 2.0f / (1.0f + __expf(-2.0f*x)) - 1.0f; }
__device__ __forceinline__ v8s u4v(uint4 q) { union { uint4 q; v8s v; } c; c.q = q; return c.v; }

// M=1-replicated A-fragments from one fp32 LDS vector
__device__ __forceinline__ void build_mv(const float* __restrict__ vec, int quad, v8s* av)
{
  #pragma unroll
  for (int ks = 0; ks < 8; ++ks) {
    const float4 a = *(const float4*)(vec + ks*32 + quad*8);
    const float4 c = *(const float4*)(vec + ks*32 + quad*8 + 4);
    union { unsigned u[4]; v8s v; } cv;
    cv.u[0] = pack2(a.x, a.y); cv.u[1] = pack2(a.z, a.w);
    cv.u[2] = pack2(c.x, c.y); cv.u[3] = pack2(c.z, c.w);
    av[ks] = cv.v;
  }
}
// same but from elementwise sum of two vectors
__device__ __forceinline__ void build_mv2(const float* __restrict__ va,
                                          const float* __restrict__ vb, int quad, v8s* av)
{
  #pragma unroll
  for (int ks = 0; ks < 8; ++ks) {
    const float4 a = *(const float4*)(va + ks*32 + quad*8);
    const float4 b = *(const float4*)(vb + ks*32 + quad*8);
    const float4 c = *(const float4*)(va + ks*32 + quad*8 + 4);
    const float4 d = *(const float4*)(vb + ks*32 + quad*8 + 4);
    union { unsigned u[4]; v8s v; } cv;
    cv.u[0] = pack2(a.x+b.x, a.y+b.y); cv.u[1] = pack2(a.z+b.z, a.w+b.w);
    cv.u[2] = pack2(c.x+d.x, c.y+d.y); cv.u[3] = pack2(c.z+d.z, c.w+d.w);
    av[ks] = cv.v;
  }
}

// per-batch barrier among 8 same-XCD blocks, monotonic counter
__device__ __forceinline__ void bbar(unsigned* cnt, unsigned& seq)
{
  __syncthreads();
  seq += 8;
  if (threadIdx.x == 0) {
    __threadfence();
    __hip_atomic_fetch_add(cnt, 1u, __ATOMIC_RELEASE, __HIP_MEMORY_SCOPE_AGENT);
    while (__hip_atomic_load(cnt, __ATOMIC_ACQUIRE, __HIP_MEMORY_SCOPE_AGENT) < seq)
      __builtin_amdgcn_s_sleep(1);
    __threadfence();
  }
  __syncthreads();
}

// ---------- prep 1: output L, zero barriers/ancestors, pack weights ----------
__global__ void __launch_bounds__(256) prep_init(
    const int* __restrict__ tg, const float* __restrict__ Wx,
    const float* __restrict__ Wh, const float* __restrict__ W1,
    float* __restrict__ ws, float* __restrict__ out)
{
  const int stride = gridDim.x * blockDim.x;
  const int t0 = blockIdx.x * blockDim.x + threadIdx.x;

  for (int i = t0; i < Bz*Nn*Nn; i += stride) {         // L = tril(targets, -1)
    int col = i & (Nn-1), row = (i >> 7) & (Nn-1);
    out[i] = (col < row) ? (float)tg[i] : 0.0f;
  }
  for (int i = t0; i < Bz; i += stride) out[Bz*Nn*Nn + i] = 0.0f;

  unsigned* BARu = (unsigned*)(ws + WS_BAR);
  for (int i = t0; i < Bz*32; i += stride) BARu[i] = 0u;
  unsigned* AMGu = (unsigned*)(ws + WS_AMG);
  for (int i = t0; i < Bz*Nn*4; i += stride) AMGu[i] = 0u;

  // B-frag packing: uint (lane l, word jw) = bf16pair W[k][n],W[k+1][n];
  // k = ks*32 + (l>>4)*8 + 2*jw ; n = tile_local*16 + (l&15)
  // regions: [0,48) Wh | [48,80) W1b | [80,128) Wx | [128,160) W1a
  unsigned* Wb = (unsigned*)(ws + WS_WB);
  for (int i = t0; i < 160*2048; i += stride) {
    int jw = i & 3, l = (i >> 2) & 63, ks = (i >> 8) & 7, nt = i >> 11;
    int k = ks*32 + (l >> 4)*8 + 2*jw;
    int n16 = l & 15;
    float lo, hi;
    if (nt < 48)       { int c = nt*16 + n16;        lo = Wh[k*Gg + c];      hi = Wh[(k+1)*Gg + c]; }
    else if (nt < 80)  { int f = (nt-48)*16 + n16;   lo = W1[(Hh+k)*Ff + f]; hi = W1[(Hh+k+1)*Ff + f]; }
    else if (nt < 128) { int c = (nt-80)*16 + n16;   lo = Wx[k*Gg + c];      hi = Wx[(k+1)*Gg + c]; }
    else               { int f = (nt-128)*16 + n16;  lo = W1[k*Ff + f];      hi = W1[(k+1)*Ff + f]; }
    Wb[i] = pack2(lo, hi);
  }
}

// ---------- prep 2: per-batch h0, gh0 = h0@Wh+bh, zW1 = z@W1c ----------
__global__ void __launch_bounds__(256) prep_batch(
    const float* __restrict__ z, const float* __restrict__ Wi,
    const float* __restrict__ bi, const float* __restrict__ Wh,
    const float* __restrict__ bh, const float* __restrict__ W1,
    float* __restrict__ ws)
{
  const int b = blockIdx.x, tid = threadIdx.x;
  __shared__ float zs[Dd], h0s[Hh];
  zs[tid] = z[b*Dd + tid];
  __syncthreads();
  float acc = bi[tid];
  for (int d = 0; d < Dd; ++d) acc = fmaf(zs[d], Wi[d*Hh + tid], acc);
  const float h0 = tanhf(acc);
  h0s[tid] = h0;
  ws[WS_H0 + b*Hh + tid] = h0;
  __syncthreads();
  for (int g = tid; g < Gg; g += 256) {
    float a = bh[g];
    for (int h = 0; h < Hh; ++h) a = fmaf(h0s[h], Wh[h*Gg + g], a);
    ws[WS_GH0 + b*Gg + g] = a;
  }
  for (int f = tid; f < Ff; f += 256) {
    float a = 0.0f;
    for (int d = 0; d < Dd; ++d) a = fmaf(zs[d], W1[(2*Hh + d)*Ff + f], a);
    ws[WS_ZW1 + b*Ff + f] = a;
  }
}

// ---------- main: 256 blocks (batch b = blk%32, slice r = blk/32 -> XCD b%8) ----------
__global__ void __launch_bounds__(NT, 2) decoder_main(
    const int* __restrict__ tg,
    const float* __restrict__ bx, const float* __restrict__ bh,
    const float* __restrict__ b1, const float* __restrict__ W2,
    const float* __restrict__ b2,
    float* __restrict__ ws, float* __restrict__ out)
{
  const int blk = blockIdx.x;
  const int b = blk & 31, r = blk >> 5;
  const int tid = threadIdx.x;
  const int lane = tid & 63, wv = tid >> 6;
  const int c16 = lane & 15, quad = lane >> 4;

  extern __shared__ char smem[];
  uint4* SW4 = (uint4*)(smem + SM_SW);
  unsigned short* SST = (unsigned short*)(smem + SM_SST);
  uint4* SST4 = (uint4*)(smem + SM_SST);
  unsigned short* NLDS = (unsigned short*)(smem + SM_NLDS);
  unsigned* NLDSu = (unsigned*)(smem + SM_NLDS);
  uint4* NLDS4 = (uint4*)(smem + SM_NLDS);
  float* PS   = (float*)(smem + SM_PS);
  float* HPF  = (float*)(smem + SM_HPF);
  float* GX1  = (float*)(smem + SM_GX1);
  float* GX2  = (float*)(smem + SM_GX2);
  float* BASE = (float*)(smem + SM_BASE);
  float* BXS  = (float*)(smem + SM_BXS);
  float* BHS  = (float*)(smem + SM_BHS);
  float* GH0S = (float*)(smem + SM_GH0S);
  float* ZB1S = (float*)(smem + SM_ZB1S);
  float* H0S  = (float*)(smem + SM_H0S);
  float* PSN  = (float*)(smem + SM_PSN);
  float* LOGI = (float*)(smem + SM_LOGI);
  float* ROWT = (float*)(smem + SM_ROWT);
  unsigned* ANCW = (unsigned*)(smem + SM_ANCW);
  float* LL = (float*)(smem + SM_LL);

  const float* __restrict__ h0g  = ws + WS_H0  + b*Hh;
  const float* __restrict__ gh0g = ws + WS_GH0 + b*Gg;
  const float* __restrict__ zW1g = ws + WS_ZW1 + b*Ff;
  float* __restrict__ XHg  = ws + WS_XH  + b*Hh;
  float* __restrict__ PSXg = ws + WS_PSX + b*Hh;
  float* __restrict__ LOGPg = ws + WS_LOGP + b*8*Nn;
  unsigned* AMGu = (unsigned*)(ws + WS_AMG) + b*Nn*4;
  const uint4* AMG4 = (const uint4*)((unsigned*)(ws + WS_AMG)) + b*Nn;
  unsigned* bar = (unsigned*)(ws + WS_BAR) + b*32;
  uint4* XS4 = (uint4*)(ws + WS_XS) + b*4096;   // [8mt][8ks][64] uint4
  const uint4* WB4 = (const uint4*)(ws + WS_WB);

  // ---- prologue ----
  for (int i = tid; i < 16384; i += NT) ((unsigned*)SST)[i] = 0u;   // zero mirror
  // load this block's weight slices to LDS (10 tiles x 512 uint4)
  for (int i = tid; i < 5120; i += NT) {
    const int lt = i >> 9, q = i & 511;
    int gt;
    if (lt < 6) { const int gate = lt >> 1, tt = lt & 1; gt = gate*16 + 2*r + tt; }
    else        { gt = 48 + 4*r + (lt - 6); }
    SW4[lt*512 + q] = WB4[gt*512 + q];
  }
  if (tid < Hh) PS[tid] = h0g[tid];
  if (tid < 32) H0S[tid] = h0g[32*r + tid];
  if (tid < 96) {
    const int g = tid >> 5, hcl = tid & 31;
    const int col = g*256 + 32*r + hcl;
    BXS[tid] = bx[col]; BHS[tid] = bh[col]; GH0S[tid] = gh0g[col];
  }
  if (tid >= 96 && tid < 160) { const int f = 64*r + (tid - 96); ZB1S[tid-96] = zW1g[f] + b1[f]; }
  if (tid == 160) *LL = 0.0f;
  float w2r[4];
  #pragma unroll
  for (int ft = 0; ft < 4; ++ft) w2r[ft] = W2[64*r + ft*16 + c16];
  const float b2v = b2[0];
  unsigned bseq = 0;
  __syncthreads();
  if (tid < Hh) {   // mirror row 0 = h0
    const int c = tid;
    SST[(c>>5)*512 + ((c>>3)&3)*128 + (c&7)] = f2bf(PS[c]);
  }
  __syncthreads();

  for (int t = 1; t < Nn; ++t) {
    const float invt  = 1.0f / (float)t;
    const float invt1 = 1.0f / (float)(t + 1);
    const int Mtot = (t + 16) >> 4;     // GRU rows 0..t
    const int Mlog = (t + 15) >> 4;     // logit rows 0..t-1
    const int mtc = t >> 4;             // = Mtot-1

    // ---- phase A: gx slice = psum@Wx_slice (waves 0..5, one tile each) ----
    if (wv < 6) {
      v8s av[8]; build_mv(PS, quad, av);
      const int g = wv >> 1, tt = wv & 1;
      const uint4* Bp = WB4 + (80 + g*16 + 2*r + tt)*512 + lane;
      f4 c = {0.0f,0.0f,0.0f,0.0f};
      #pragma unroll
      for (int ks = 0; ks < 8; ++ks) c = MFMA(av[ks], u4v(Bp[ks*64]), c);
      if (quad == 0) GX1[g*32 + tt*16 + c16] = c[0];
    }
    __syncthreads();
    // h_prov slice + exchange write
    if (tid < 32) {
      const int hcl = tid;
      const float gxr = GX1[hcl]*invt    + BXS[hcl];
      const float gxu = GX1[32+hcl]*invt + BXS[32+hcl];
      const float gxn = GX1[64+hcl]*invt + BXS[64+hcl];
      const float rv = sigm(gxr + GH0S[hcl]);
      const float uv = sigm(gxu + GH0S[32+hcl]);
      const float nv = tanh_fast(gxn + rv*GH0S[64+hcl]);
      XHg[32*r + hcl] = (1.0f-uv)*nv + uv*H0S[hcl];
    }
    bbar(bar, bseq);   // B1: h_prov complete

    // ---- phase B1: gather h_prov, zero scratch, load targets row ----
    if (tid < Hh) {
      HPF[tid] = XHg[tid];
      NLDSu[mtc*256 + tid] = 0u;       // zero staging chunk for rows > t
    } else if (tid < Hh + Nn) {
      const int j = tid - Hh;
      ROWT[j] = (r == 0 && j < t) ? (float)tg[b*Nn*Nn + t*Nn + j] : 0.0f;
      LOGI[j] = 0.0f;
    } else if (tid < Hh + Nn + 32) {
      PSN[tid - Hh - Nn] = 0.0f;
    } else if (tid < Hh + Nn + 36) {
      ANCW[tid - Hh - Nn - 32] = 0u;
    }
    __syncthreads();

    // ---- phase B2: mirror row t = h_prov; matvec slices gx2/base ----
    if (tid < Hh) {
      const int c = tid;
      SST[(mtc*8 + (c>>5))*512 + (((c>>3)&3)*16 + (t&15))*8 + (c&7)] = f2bf(HPF[c]);
    }
    for (int j = wv; j < 10; j += 8) {
      if (j < 6) {
        v8s av[8]; build_mv2(PS, HPF, quad, av);
        const int g = j >> 1, tt = j & 1;
        const uint4* Bp = WB4 + (80 + g*16 + 2*r + tt)*512 + lane;
        f4 c = {0.0f,0.0f,0.0f,0.0f};
        #pragma unroll
        for (int ks = 0; ks < 8; ++ks) c = MFMA(av[ks], u4v(Bp[ks*64]), c);
        if (quad == 0) GX2[g*32 + tt*16 + c16] = c[0]*invt1 + BXS[g*32 + tt*16 + c16];
      } else {
        v8s av[8]; build_mv(HPF, quad, av);
        const int ft = j - 6;
        const uint4* Bp = WB4 + (128 + 4*r + ft)*512 + lane;
        f4 c = {0.0f,0.0f,0.0f,0.0f};
        #pragma unroll
        for (int ks = 0; ks < 8; ++ks) c = MFMA(av[ks], u4v(Bp[ks*64]), c);
        if (quad == 0) BASE[ft*16 + c16] = c[0] + ZB1S[ft*16 + c16];
      }
    }
    __syncthreads();

    // ---- phase C: main GEMM jobs from LDS (weights + state mirror) ----
    const int njobs = 2*Mtot + Mlog;
    for (int j = wv; j < njobs; j += 8) {
      if (j < 2*Mtot) {
        // GRU job: m-tile mt, 16-col tile ct of this block's 32-col slice
        const int mt = j >> 1, ct = j & 1;
        v8s af[8];
        #pragma unroll
        for (int ks = 0; ks < 8; ++ks)
          af[ks] = *(const v8s*)(SST + (mt*8 + ks)*512 + lane*8);
        f4 cr = {0.0f,0.0f,0.0f,0.0f}, cu = {0.0f,0.0f,0.0f,0.0f}, cn = {0.0f,0.0f,0.0f,0.0f};
        #pragma unroll
        for (int ks = 0; ks < 8; ++ks) {
          cr = MFMA(af[ks], u4v(SW4[((ct    )*8 + ks)*64 + lane]), cr);
          cu = MFMA(af[ks], u4v(SW4[((2 + ct)*8 + ks)*64 + lane]), cu);
          cn = MFMA(af[ks], u4v(SW4[((4 + ct)*8 + ks)*64 + lane]), cn);
        }
        const int hcl = ct*16 + c16;
        const float gxr = GX2[hcl], gxu = GX2[32+hcl], gxn = GX2[64+hcl];
        const float bhr = BHS[hcl], bhu = BHS[32+hcl], bhn = BHS[64+hcl];
        float colsum = 0.0f;
        #pragma unroll
        for (int rg = 0; rg < 4; ++rg) {
          const int row = mt*16 + quad*4 + rg;
          if (row <= t) {
            const int spi = ((hcl>>3)*16 + quad*4 + rg)*8 + (hcl & 7);
            const float old = bf2f(SST[(mt*8 + r)*512 + spi]);
            const float rv = sigm(gxr + cr[rg] + bhr);
            const float uv = sigm(gxu + cu[rg] + bhu);
            const float nv = tanh_fast(gxn + rv*(cn[rg] + bhn));
            const float ns = (1.0f-uv)*nv + uv*old;
            NLDS[mt*512 + spi] = f2bf(ns);
            colsum += ns;
          }
        }
        colsum += __shfl_down(colsum, 16);
        colsum += __shfl_down(colsum, 32);
        if (lane < 16) atomicAdd(&PSN[ct*16 + lane], colsum);
      } else {
        // logit job: m-tile, this block's 64 f-cols
        const int mt = j - 2*Mtot;
        v8s af[8];
        #pragma unroll
        for (int ks = 0; ks < 8; ++ks)
          af[ks] = *(const v8s*)(SST + (mt*8 + ks)*512 + lane*8);
        f4 cl0 = {0.0f,0.0f,0.0f,0.0f}, cl1 = {0.0f,0.0f,0.0f,0.0f};
        f4 cl2 = {0.0f,0.0f,0.0f,0.0f}, cl3 = {0.0f,0.0f,0.0f,0.0f};
        #pragma unroll
        for (int ks = 0; ks < 8; ++ks) {
          cl0 = MFMA(af[ks], u4v(SW4[((6)*8 + ks)*64 + lane]), cl0);
          cl1 = MFMA(af[ks], u4v(SW4[((7)*8 + ks)*64 + lane]), cl1);
          cl2 = MFMA(af[ks], u4v(SW4[((8)*8 + ks)*64 + lane]), cl2);
          cl3 = MFMA(af[ks], u4v(SW4[((9)*8 + ks)*64 + lane]), cl3);
        }
        #pragma unroll
        for (int rg = 0; rg < 4; ++rg) {
          float v = fmaxf(cl0[rg] + BASE[c16],      0.0f)*w2r[0]
                  + fmaxf(cl1[rg] + BASE[16+c16],   0.0f)*w2r[1]
                  + fmaxf(cl2[rg] + BASE[32+c16],   0.0f)*w2r[2]
                  + fmaxf(cl3[rg] + BASE[48+c16],   0.0f)*w2r[3];
          v += __shfl_xor(v, 1); v += __shfl_xor(v, 2);
          v += __shfl_xor(v, 4); v += __shfl_xor(v, 8);
          const int row = mt*16 + quad*4 + rg;
          if (c16 == 0 && row < t) atomicAdd(&LOGI[row], v);
        }
      }
    }
    __syncthreads();

    // ---- copy-out: new-state slice, psum slice, logit partials ----
    if (tid < Mtot*64) {
      const int mt = tid >> 6, q = tid & 63;
      XS4[(mt*8 + r)*64 + q] = NLDS4[tid];
    }
    if (tid >= 256 && tid < 384) LOGPg[r*Nn + (tid - 256)] = LOGI[tid - 256];
    if (tid >= 384 && tid < 416) PSXg[32*r + (tid - 384)] = PSN[tid - 384];
    bbar(bar, bseq);   // B2: states/logits/psum complete

    // ---- update: refresh mirror + psum; r==0 computes ll + ancestors ----
    for (int i = tid; i < Mtot*512; i += NT) SST4[i] = XS4[i];
    if (tid < Hh) PS[tid] = PSXg[tid];
    if (r == 0) {
      if (tid < Nn && tid < t && ROWT[tid] > 0.5f) {
        const uint4 am = AMG4[tid];
        atomicOr(&ANCW[0], am.x); atomicOr(&ANCW[1], am.y);
        atomicOr(&ANCW[2], am.z); atomicOr(&ANCW[3], am.w);
      }
      __syncthreads();
      float term = 0.0f;
      if (tid < t) {
        float lsum = b2v;
        #pragma unroll
        for (int rr = 0; rr < 8; ++rr) lsum += LOGPg[rr*Nn + tid];
        const float anc = (float)((ANCW[tid >> 5] >> (tid & 31)) & 1u);
        float q = sigm(lsum) * (1.0f - 0.5f*anc);
        q = fminf(fmaxf(q, 1e-6f), 1.0f - 1e-6f);
        term = ROWT[tid]*logf(q) + (1.0f - ROWT[tid])*log1pf(-q);
      }
      if (wv < 2) {
        #pragma unroll
        for (int off = 32; off; off >>= 1) term += __shfl_down(term, off);
        if (lane == 0) atomicAdd(LL, term);
        const unsigned long long bal = __ballot(tid < t && ROWT[tid] > 0.5f);
        if (lane == 0) {
          AMGu[t*4 + 2*wv]     = (unsigned)bal         | ANCW[2*wv];
          AMGu[t*4 + 2*wv + 1] = (unsigned)(bal >> 32) | ANCW[2*wv + 1];
        }
      }
    }
    __syncthreads();
  }

  if (r == 0 && tid == 0) out[Bz*Nn*Nn + b] = *LL;
}

extern "C" void kernel_launch(void* const* d_in, const int* in_sizes, int n_in,
                              void* d_out, int out_size, void* d_ws, size_t ws_size,
                              hipStream_t stream)
{
  const float* z  = (const float*)d_in[0];
  const int*   tg = (const int*)  d_in[1];
  const float* Wi = (const float*)d_in[2];
  const float* bi = (const float*)d_in[3];
  const float* Wx = (const float*)d_in[4];
  const float* Wh = (const float*)d_in[5];
  const float* bx = (const float*)d_in[6];
  const float* bh = (const float*)d_in[7];
  const float* W1 = (const float*)d_in[8];
  const float* b1 = (const float*)d_in[9];
  const float* W2 = (const float*)d_in[10];
  const float* b2 = (const float*)d_in[11];
  float* out = (float*)d_out;
  float* ws  = (float*)d_ws;

  hipFuncSetAttribute((const void*)decoder_main,
                      hipFuncAttributeMaxDynamicSharedMemorySize, SMEM_SZ);

  hipLaunchKernelGGL(prep_init, dim3(512), dim3(256), 0, stream, tg, Wx, Wh, W1, ws, out);
  hipLaunchKernelGGL(prep_batch, dim3(Bz), dim3(256), 0, stream, z, Wi, bi, Wh, bh, W1, ws);

  void* args[] = { (void*)&tg, (void*)&bx, (void*)&bh, (void*)&b1,
                   (void*)&W2, (void*)&b2, (void*)&ws, (void*)&out };
  hipLaunchCooperativeKernel((void*)decoder_main, dim3(256), dim3(NT),
                             args, SMEM_SZ, stream);
}

// Round 6
// 2064.809 us; speedup vs baseline: 6.3547x; 2.6477x over previous
//
#include <hip/hip_runtime.h>
#include <hip/hip_bf16.h>
#include <math.h>

// Problem constants
#define Bz 32
#define Nn 128
#define Hh 256
#define Dd 256
#define Ff 512
#define Gg 768
#define NT 512          // 8 waves per block; 256 blocks = 32 batches x 8 col-slices

typedef short v8s __attribute__((ext_vector_type(8)));   // 8 bf16
typedef float f4  __attribute__((ext_vector_type(4)));   // MFMA C/D
#define MFMA(a,b,c) __builtin_amdgcn_mfma_f32_16x16x32_bf16(a,b,c,0,0,0)

// Workspace layout (float elements)
#define WS_H0    0                          // [B][256]
#define WS_GH0   (WS_H0 + Bz*Hh)            // [B][768]
#define WS_ZW1   (WS_GH0 + Bz*Gg)           // [B][512]
#define WS_XH    (WS_ZW1 + Bz*Ff)           // [B][256]   h_prov exchange
#define WS_PSX   (WS_XH + Bz*Hh)            // [B][256]   psum exchange
#define WS_LOGP  (WS_PSX + Bz*Hh)           // [B][8][128] logit partials
#define WS_BAR   (WS_LOGP + Bz*8*Nn)        // [B][32] uint barrier counters (1 line apart)
#define WS_XS    (WS_BAR + Bz*32)           // [B][8mt][8ks][128] u64 state exchange (64KB/b)
#define WS_WB    (WS_XS + Bz*16384)         // [160][8][64][4] uint B-frag packed weights
#define WS_TOTAL (WS_WB + 160*2048)

// LDS layout (bytes) — total 163488 <= 163840
#define SM_SW    0         // [10 lt][8 ks][64 lane] uint4 : 6 Wh-tiles + 4 W1b-tiles (81920)
#define SM_SST   81920     // ushort[8mt][8ks][512] bf16 state mirror (65536)
#define SM_NLDS  147456    // ushort[8mt][512] new-state own-slice staging (8192)
#define SM_PS    155648    // float[256]
#define SM_HPF   156672    // float[256]
#define SM_GX1   157696    // float[96]
#define SM_GX2   158080    // float[96]
#define SM_BASE  158464    // float[64]
#define SM_BXS   158720    // float[96]
#define SM_BHS   159104    // float[96]
#define SM_GH0S  159488    // float[96]
#define SM_ZB1S  159872    // float[64]
#define SM_H0S   160128    // float[32]
#define SM_PSN   160256    // float[32]
#define SM_LOGI  160384    // float[128]
#define SM_ROWT  160896    // float[128]
#define SM_AMASK 161408    // uint[128][4] (r==0 only)
#define SM_ANCW  163456    // uint[4]
#define SM_LL    163472    // float
#define SMEM_SZ  163488

__device__ __forceinline__ unsigned short f2bf(float x) {
  unsigned u = __float_as_uint(x);
  u = u + 0x7fffu + ((u >> 16) & 1u);   // RNE
  return (unsigned short)(u >> 16);
}
__device__ __forceinline__ unsigned pack2(float e, float o) {
  return (unsigned)f2bf(e) | ((unsigned)f2bf(o) << 16);
}
__device__ __forceinline__ unsigned pkbf(float x, float y) {
  __hip_bfloat162 h = __float22bfloat162_rn(make_float2(x, y));
  union { __hip_bfloat162 h; unsigned u; } c; c.h = h; return c.u;
}
__device__ __forceinline__ float bf2f(unsigned short s) {
  return __uint_as_float(((unsigned)s) << 16);
}
__device__ __forceinline__ float sigm(float x) { return 1.0f / (1.0f + __expf(-x)); }
__device__ __forceinline__ float tanh_fast(float x) { return 2.0f / (1.0f + __expf(-2.0f*x)) - 1.0f; }
__device__ __forceinline__ v8s u4v(uint4 q) { union { uint4 q; v8s v; } c; c.q = q; return c.v; }

// Relaxed AGENT atomics: coherent at device point (L3), no L2 writeback/invalidate.
__device__ __forceinline__ void ast32(unsigned* p, unsigned v) {
  __hip_atomic_store(p, v, __ATOMIC_RELAXED, __HIP_MEMORY_SCOPE_AGENT);
}
__device__ __forceinline__ unsigned ald32(const unsigned* p) {
  return __hip_atomic_load(p, __ATOMIC_RELAXED, __HIP_MEMORY_SCOPE_AGENT);
}
__device__ __forceinline__ void ast64(unsigned long long* p, unsigned long long v) {
  __hip_atomic_store(p, v, __ATOMIC_RELAXED, __HIP_MEMORY_SCOPE_AGENT);
}
__device__ __forceinline__ unsigned long long ald64(const unsigned long long* p) {
  return __hip_atomic_load(p, __ATOMIC_RELAXED, __HIP_MEMORY_SCOPE_AGENT);
}

// per-batch barrier among 8 blocks: NO fences. Each thread drains its own vm ops,
// block-barrier, then one relaxed L3 atomic signal + spin.
__device__ __forceinline__ void bbar(unsigned* cnt, unsigned& seq)
{
  __builtin_amdgcn_s_waitcnt(0x0F70);   // vmcnt(0): this thread's stores complete
  __syncthreads();
  seq += 8;
  if (threadIdx.x == 0) {
    __hip_atomic_fetch_add(cnt, 1u, __ATOMIC_RELAXED, __HIP_MEMORY_SCOPE_AGENT);
    while (__hip_atomic_load(cnt, __ATOMIC_RELAXED, __HIP_MEMORY_SCOPE_AGENT) < seq)
      __builtin_amdgcn_s_sleep(2);
  }
  __syncthreads();
}

// ---------- prep 1: output L, zero barriers, pack weights ----------
__global__ void __launch_bounds__(256) prep_init(
    const int* __restrict__ tg, const float* __restrict__ Wx,
    const float* __restrict__ Wh, const float* __restrict__ W1,
    float* __restrict__ ws, float* __restrict__ out)
{
  const int stride = gridDim.x * blockDim.x;
  const int t0 = blockIdx.x * blockDim.x + threadIdx.x;

  for (int i = t0; i < Bz*Nn*Nn; i += stride) {         // L = tril(targets, -1)
    int col = i & (Nn-1), row = (i >> 7) & (Nn-1);
    out[i] = (col < row) ? (float)tg[i] : 0.0f;
  }
  for (int i = t0; i < Bz; i += stride) out[Bz*Nn*Nn + i] = 0.0f;

  unsigned* BARu = (unsigned*)(ws + WS_BAR);
  for (int i = t0; i < Bz*32; i += stride) BARu[i] = 0u;

  // B-frag packing: uint (lane l, word jw) = bf16pair W[k][n],W[k+1][n];
  // k = ks*32 + (l>>4)*8 + 2*jw ; n = tile_local*16 + (l&15)
  // regions: [0,48) Wh | [48,80) W1b | [80,128) Wx | [128,160) W1a
  unsigned* Wb = (unsigned*)(ws + WS_WB);
  for (int i = t0; i < 160*2048; i += stride) {
    int jw = i & 3, l = (i >> 2) & 63, ks = (i >> 8) & 7, nt = i >> 11;
    int k = ks*32 + (l >> 4)*8 + 2*jw;
    int n16 = l & 15;
    float lo, hi;
    if (nt < 48)       { int c = nt*16 + n16;        lo = Wh[k*Gg + c];      hi = Wh[(k+1)*Gg + c]; }
    else if (nt < 80)  { int f = (nt-48)*16 + n16;   lo = W1[(Hh+k)*Ff + f]; hi = W1[(Hh+k+1)*Ff + f]; }
    else if (nt < 128) { int c = (nt-80)*16 + n16;   lo = Wx[k*Gg + c];      hi = Wx[(k+1)*Gg + c]; }
    else               { int f = (nt-128)*16 + n16;  lo = W1[k*Ff + f];      hi = W1[(k+1)*Ff + f]; }
    Wb[i] = pack2(lo, hi);
  }
}

// ---------- prep 2: per-batch h0, gh0 = h0@Wh+bh, zW1 = z@W1c ----------
__global__ void __launch_bounds__(256) prep_batch(
    const float* __restrict__ z, const float* __restrict__ Wi,
    const float* __restrict__ bi, const float* __restrict__ Wh,
    const float* __restrict__ bh, const float* __restrict__ W1,
    float* __restrict__ ws)
{
  const int b = blockIdx.x, tid = threadIdx.x;
  __shared__ float zs[Dd], h0s[Hh];
  zs[tid] = z[b*Dd + tid];
  __syncthreads();
  float acc = bi[tid];
  for (int d = 0; d < Dd; ++d) acc = fmaf(zs[d], Wi[d*Hh + tid], acc);
  const float h0 = tanhf(acc);
  h0s[tid] = h0;
  ws[WS_H0 + b*Hh + tid] = h0;
  __syncthreads();
  for (int g = tid; g < Gg; g += 256) {
    float a = bh[g];
    for (int h = 0; h < Hh; ++h) a = fmaf(h0s[h], Wh[h*Gg + g], a);
    ws[WS_GH0 + b*Gg + g] = a;
  }
  for (int f = tid; f < Ff; f += 256) {
    float a = 0.0f;
    for (int d = 0; d < Dd; ++d) a = fmaf(zs[d], W1[(2*Hh + d)*Ff + f], a);
    ws[WS_ZW1 + b*Ff + f] = a;
  }
}

// M=1-replicated A-fragments from one fp32 LDS vector
__device__ __forceinline__ void build_mv(const float* __restrict__ vec, int quad, v8s* av)
{
  #pragma unroll
  for (int ks = 0; ks < 8; ++ks) {
    const float4 a = *(const float4*)(vec + ks*32 + quad*8);
    const float4 c = *(const float4*)(vec + ks*32 + quad*8 + 4);
    union { unsigned u[4]; v8s v; } cv;
    cv.u[0] = pkbf(a.x, a.y); cv.u[1] = pkbf(a.z, a.w);
    cv.u[2] = pkbf(c.x, c.y); cv.u[3] = pkbf(c.z, c.w);
    av[ks] = cv.v;
  }
}
__device__ __forceinline__ void build_mv2(const float* __restrict__ va,
                                          const float* __restrict__ vb, int quad, v8s* av)
{
  #pragma unroll
  for (int ks = 0; ks < 8; ++ks) {
    const float4 a = *(const float4*)(va + ks*32 + quad*8);
    const float4 b = *(const float4*)(vb + ks*32 + quad*8);
    const float4 c = *(const float4*)(va + ks*32 + quad*8 + 4);
    const float4 d = *(const float4*)(vb + ks*32 + quad*8 + 4);
    union { unsigned u[4]; v8s v; } cv;
    cv.u[0] = pkbf(a.x+b.x, a.y+b.y); cv.u[1] = pkbf(a.z+b.z, a.w+b.w);
    cv.u[2] = pkbf(c.x+d.x, c.y+d.y); cv.u[3] = pkbf(c.z+d.z, c.w+d.w);
    av[ks] = cv.v;
  }
}

// ---------- main: 256 blocks (batch b = blk%32, slice r = blk/32) ----------
__global__ void __launch_bounds__(NT, 2) decoder_main(
    const int* __restrict__ tg,
    const float* __restrict__ bx, const float* __restrict__ bh,
    const float* __restrict__ b1, const float* __restrict__ W2,
    const float* __restrict__ b2,
    float* __restrict__ ws, float* __restrict__ out)
{
  const int blk = blockIdx.x;
  const int b = blk & 31, r = blk >> 5;
  const int tid = threadIdx.x;
  const int lane = tid & 63, wv = tid >> 6;
  const int c16 = lane & 15, quad = lane >> 4;

  extern __shared__ char smem[];
  uint4* SW4 = (uint4*)(smem + SM_SW);
  unsigned short* SST = (unsigned short*)(smem + SM_SST);
  unsigned long long* SST64 = (unsigned long long*)(smem + SM_SST);
  unsigned short* NLDS = (unsigned short*)(smem + SM_NLDS);
  unsigned* NLDSu = (unsigned*)(smem + SM_NLDS);
  unsigned long long* NLDS64 = (unsigned long long*)(smem + SM_NLDS);
  float* PS   = (float*)(smem + SM_PS);
  float* HPF  = (float*)(smem + SM_HPF);
  float* GX1  = (float*)(smem + SM_GX1);
  float* GX2  = (float*)(smem + SM_GX2);
  float* BASE = (float*)(smem + SM_BASE);
  float* BXS  = (float*)(smem + SM_BXS);
  float* BHS  = (float*)(smem + SM_BHS);
  float* GH0S = (float*)(smem + SM_GH0S);
  float* ZB1S = (float*)(smem + SM_ZB1S);
  float* H0S  = (float*)(smem + SM_H0S);
  float* PSN  = (float*)(smem + SM_PSN);
  float* LOGI = (float*)(smem + SM_LOGI);
  float* ROWT = (float*)(smem + SM_ROWT);
  unsigned* AMASK = (unsigned*)(smem + SM_AMASK);
  unsigned* ANCW = (unsigned*)(smem + SM_ANCW);
  float* LL = (float*)(smem + SM_LL);

  const float* __restrict__ h0g  = ws + WS_H0  + b*Hh;
  const float* __restrict__ gh0g = ws + WS_GH0 + b*Gg;
  const float* __restrict__ zW1g = ws + WS_ZW1 + b*Ff;
  unsigned* XHg  = (unsigned*)(ws + WS_XH) + b*Hh;
  unsigned long long* XH64 = (unsigned long long*)((unsigned*)(ws + WS_XH) + b*Hh);
  unsigned long long* PSX64 = (unsigned long long*)((unsigned*)(ws + WS_PSX) + b*Hh);
  unsigned long long* LOGP64 = (unsigned long long*)((unsigned*)(ws + WS_LOGP) + b*8*Nn);
  unsigned* LOGPg = (unsigned*)(ws + WS_LOGP) + b*8*Nn;
  unsigned* bar = (unsigned*)(ws + WS_BAR) + b*32;
  unsigned long long* XS64 = (unsigned long long*)(ws + WS_XS) + b*8192;  // [8mt][8ks][128]
  const uint4* WB4 = (const uint4*)(ws + WS_WB);

  // ---- prologue ----
  for (int i = tid; i < 16384; i += NT) ((unsigned*)SST)[i] = 0u;   // zero mirror
  for (int i = tid; i < 5120; i += NT) {   // weight slices -> LDS (10 tiles)
    const int lt = i >> 9, q = i & 511;
    int gt;
    if (lt < 6) { const int gate = lt >> 1, tt = lt & 1; gt = gate*16 + 2*r + tt; }
    else        { gt = 48 + 4*r + (lt - 6); }
    SW4[lt*512 + q] = WB4[gt*512 + q];
  }
  if (tid < Hh) PS[tid] = h0g[tid];
  if (tid < 32) H0S[tid] = h0g[32*r + tid];
  if (tid < 96) {
    const int g = tid >> 5, hcl = tid & 31;
    const int col = g*256 + 32*r + hcl;
    BXS[tid] = bx[col]; BHS[tid] = bh[col]; GH0S[tid] = gh0g[col];
  }
  if (tid >= 96 && tid < 160) { const int f = 64*r + (tid - 96); ZB1S[tid-96] = zW1g[f] + b1[f]; }
  if (tid == 160) *LL = 0.0f;
  for (int i = tid; i < Nn*4; i += NT) AMASK[i] = 0u;
  float w2r[4];
  #pragma unroll
  for (int ft = 0; ft < 4; ++ft) w2r[ft] = W2[64*r + ft*16 + c16];
  const float b2v = b2[0];
  unsigned bseq = 0;
  __syncthreads();
  if (tid < Hh) {   // mirror row 0 = h0
    const int c = tid;
    SST[(c>>5)*512 + ((c>>3)&3)*128 + (c&7)] = f2bf(PS[c]);
  }
  __syncthreads();

  for (int t = 1; t < Nn; ++t) {
    const float invt  = 1.0f / (float)t;
    const float invt1 = 1.0f / (float)(t + 1);
    const int Mtot = (t + 16) >> 4;     // GRU rows 0..t
    const int Mlog = (t + 15) >> 4;     // logit rows 0..t-1
    const int mtc = t >> 4;             // tile holding row t

    // ---- phase A: gx1 slice = psum@Wx_slice (waves 0..5) ----
    if (wv < 6) {
      v8s av[8]; build_mv(PS, quad, av);
      const int g = wv >> 1, tt = wv & 1;
      const uint4* Bp = WB4 + (80 + g*16 + 2*r + tt)*512 + lane;
      f4 c = {0.0f,0.0f,0.0f,0.0f};
      #pragma unroll
      for (int ks = 0; ks < 8; ++ks) c = MFMA(av[ks], u4v(Bp[ks*64]), c);
      if (quad == 0) GX1[g*32 + tt*16 + c16] = c[0];
    }
    __syncthreads();
    if (tid < 32) {   // h_prov slice -> exchange (atomic 32b)
      const int hcl = tid;
      const float gxr = GX1[hcl]*invt    + BXS[hcl];
      const float gxu = GX1[32+hcl]*invt + BXS[32+hcl];
      const float gxn = GX1[64+hcl]*invt + BXS[64+hcl];
      const float rv = sigm(gxr + GH0S[hcl]);
      const float uv = sigm(gxu + GH0S[32+hcl]);
      const float nv = tanh_fast(gxn + rv*GH0S[64+hcl]);
      ast32(XHg + 32*r + hcl, __float_as_uint((1.0f-uv)*nv + uv*H0S[hcl]));
    }
    bbar(bar, bseq);   // B1: h_prov complete

    // ---- phase B1: gather h_prov (L3 atomics), zero scratch ----
    if (tid < 128) {
      const unsigned long long v = ald64(XH64 + tid);
      HPF[2*tid]   = __uint_as_float((unsigned)v);
      HPF[2*tid+1] = __uint_as_float((unsigned)(v >> 32));
    }
    if (tid < 256) NLDSu[mtc*256 + tid] = 0u;
    else if (tid < 384) {
      const int j = tid - 256;
      ROWT[j] = (r == 0 && j < t) ? (float)tg[b*Nn*Nn + t*Nn + j] : 0.0f;
      LOGI[j] = 0.0f;
    } else if (tid < 416) PSN[tid - 384] = 0.0f;
    else if (tid < 420) ANCW[tid - 416] = 0u;
    __syncthreads();

    // ---- phase B2: mirror row t; matvecs gx2/base; anc OR (r==0) ----
    if (tid < Hh) {
      const int c = tid;
      SST[(mtc*8 + (c>>5))*512 + (((c>>3)&3)*16 + (t&15))*8 + (c&7)] = f2bf(HPF[c]);
    }
    for (int j = wv; j < 10; j += 8) {
      if (j < 6) {
        v8s av[8]; build_mv2(PS, HPF, quad, av);
        const int g = j >> 1, tt = j & 1;
        const uint4* Bp = WB4 + (80 + g*16 + 2*r + tt)*512 + lane;
        f4 c = {0.0f,0.0f,0.0f,0.0f};
        #pragma unroll
        for (int ks = 0; ks < 8; ++ks) c = MFMA(av[ks], u4v(Bp[ks*64]), c);
        if (quad == 0) GX2[g*32 + tt*16 + c16] = c[0]*invt1 + BXS[g*32 + tt*16 + c16];
      } else {
        v8s av[8]; build_mv(HPF, quad, av);
        const int ft = j - 6;
        const uint4* Bp = WB4 + (128 + 4*r + ft)*512 + lane;
        f4 c = {0.0f,0.0f,0.0f,0.0f};
        #pragma unroll
        for (int ks = 0; ks < 8; ++ks) c = MFMA(av[ks], u4v(Bp[ks*64]), c);
        if (quad == 0) BASE[ft*16 + c16] = c[0] + ZB1S[ft*16 + c16];
      }
    }
    if (r == 0 && tid < Nn && tid < t && ROWT[tid] > 0.5f) {
      atomicOr(&ANCW[0], AMASK[tid*4+0]); atomicOr(&ANCW[1], AMASK[tid*4+1]);
      atomicOr(&ANCW[2], AMASK[tid*4+2]); atomicOr(&ANCW[3], AMASK[tid*4+3]);
    }
    __syncthreads();

    // ---- phase C: main GEMMs from LDS (merged GRU jobs + logit jobs) ----
    const int njobs = Mtot + Mlog;
    for (int j = wv; j < njobs; j += 8) {
      const int isG = (j < Mtot);
      const int mt = isG ? j : (j - Mtot);
      v8s af[8];
      #pragma unroll
      for (int ks = 0; ks < 8; ++ks)
        af[ks] = *(const v8s*)(SST + (mt*8 + ks)*512 + lane*8);
      if (isG) {
        f4 cr0={0,0,0,0}, cr1={0,0,0,0}, cu0={0,0,0,0}, cu1={0,0,0,0}, cn0={0,0,0,0}, cn1={0,0,0,0};
        #pragma unroll
        for (int ks = 0; ks < 8; ++ks) {
          cr0 = MFMA(af[ks], u4v(SW4[(0*8 + ks)*64 + lane]), cr0);
          cr1 = MFMA(af[ks], u4v(SW4[(1*8 + ks)*64 + lane]), cr1);
          cu0 = MFMA(af[ks], u4v(SW4[(2*8 + ks)*64 + lane]), cu0);
          cu1 = MFMA(af[ks], u4v(SW4[(3*8 + ks)*64 + lane]), cu1);
          cn0 = MFMA(af[ks], u4v(SW4[(4*8 + ks)*64 + lane]), cn0);
          cn1 = MFMA(af[ks], u4v(SW4[(5*8 + ks)*64 + lane]), cn1);
        }
        #pragma unroll
        for (int ct = 0; ct < 2; ++ct) {
          const int hcl = ct*16 + c16;
          const f4 cr = ct ? cr1 : cr0;
          const f4 cu = ct ? cu1 : cu0;
          const f4 cn = ct ? cn1 : cn0;
          const float gxr = GX2[hcl], gxu = GX2[32+hcl], gxn = GX2[64+hcl];
          const float bhr = BHS[hcl], bhu = BHS[32+hcl], bhn = BHS[64+hcl];
          float colsum = 0.0f;
          #pragma unroll
          for (int rg = 0; rg < 4; ++rg) {
            const int row = mt*16 + quad*4 + rg;
            if (row <= t) {
              const int spi = ((hcl>>3)*16 + quad*4 + rg)*8 + (hcl & 7);
              const float old = bf2f(SST[(mt*8 + r)*512 + spi]);
              const float rv = sigm(gxr + cr[rg] + bhr);
              const float uv = sigm(gxu + cu[rg] + bhu);
              const float nv = tanh_fast(gxn + rv*(cn[rg] + bhn));
              const float ns = (1.0f-uv)*nv + uv*old;
              NLDS[mt*512 + spi] = f2bf(ns);
              colsum += ns;
            }
          }
          colsum += __shfl_down(colsum, 16);
          colsum += __shfl_down(colsum, 32);
          if (lane < 16) atomicAdd(&PSN[ct*16 + lane], colsum);
        }
      } else {
        f4 cl0={0,0,0,0}, cl1={0,0,0,0}, cl2={0,0,0,0}, cl3={0,0,0,0};
        #pragma unroll
        for (int ks = 0; ks < 8; ++ks) {
          cl0 = MFMA(af[ks], u4v(SW4[(6*8 + ks)*64 + lane]), cl0);
          cl1 = MFMA(af[ks], u4v(SW4[(7*8 + ks)*64 + lane]), cl1);
          cl2 = MFMA(af[ks], u4v(SW4[(8*8 + ks)*64 + lane]), cl2);
          cl3 = MFMA(af[ks], u4v(SW4[(9*8 + ks)*64 + lane]), cl3);
        }
        #pragma unroll
        for (int rg = 0; rg < 4; ++rg) {
          float v = fmaxf(cl0[rg] + BASE[c16],    0.0f)*w2r[0]
                  + fmaxf(cl1[rg] + BASE[16+c16], 0.0f)*w2r[1]
                  + fmaxf(cl2[rg] + BASE[32+c16], 0.0f)*w2r[2]
                  + fmaxf(cl3[rg] + BASE[48+c16], 0.0f)*w2r[3];
          v += __shfl_xor(v, 1); v += __shfl_xor(v, 2);
          v += __shfl_xor(v, 4); v += __shfl_xor(v, 8);
          const int row = mt*16 + quad*4 + rg;
          if (c16 == 0 && row < t) atomicAdd(&LOGI[row], v);
        }
      }
    }
    __syncthreads();

    // ---- copy-out (all via relaxed L3 atomics): states, logits, psum ----
    for (int i = tid; i < Mtot*128; i += NT) {
      const int mt = i >> 7, q = i & 127;
      const unsigned long long v = NLDS64[i];
      ast64(XS64 + (mt*8 + r)*128 + q, v);
      SST64[(mt*8 + r)*128 + q] = v;            // own chunk updated locally
    }
    if (tid < 64) ast64(LOGP64 + r*64 + tid, ((const unsigned long long*)LOGI)[tid]);
    else if (tid < 80) ast64(PSX64 + r*16 + (tid - 64), ((const unsigned long long*)PSN)[tid - 64]);
    bbar(bar, bseq);   // B2: states/logits/psum complete

    // ---- refresh: other 7 state chunks, psum; r==0: ll + ancestor row t ----
    for (int i = tid; i < Mtot*1024; i += NT) {
      const int ks = (i >> 7) & 7;
      if (ks != r) SST64[i] = ald64(XS64 + i);
    }
    if (tid < 128) {
      const unsigned long long v = ald64(PSX64 + tid);
      PS[2*tid]   = __uint_as_float((unsigned)v);
      PS[2*tid+1] = __uint_as_float((unsigned)(v >> 32));
    }
    if (r == 0) {
      float term = 0.0f;
      if (tid < t) {
        float lsum = b2v;
        #pragma unroll
        for (int rr = 0; rr < 8; ++rr)
          lsum += __uint_as_float(ald32(LOGPg + rr*Nn + tid));
        const float anc = (float)((ANCW[tid >> 5] >> (tid & 31)) & 1u);
        float q = sigm(lsum) * (1.0f - 0.5f*anc);
        q = fminf(fmaxf(q, 1e-6f), 1.0f - 1e-6f);
        term = ROWT[tid]*logf(q) + (1.0f - ROWT[tid])*log1pf(-q);
      }
      if (wv < 2) {
        #pragma unroll
        for (int off = 32; off; off >>= 1) term += __shfl_down(term, off);
        if (lane == 0) atomicAdd(LL, term);
        const unsigned long long bal = __ballot(tid < t && ROWT[tid] > 0.5f);
        if (lane == 0) {
          AMASK[t*4 + 2*wv]     = (unsigned)bal         | ANCW[2*wv];
          AMASK[t*4 + 2*wv + 1] = (unsigned)(bal >> 32) | ANCW[2*wv + 1];
        }
      }
    }
    __syncthreads();
  }

  if (r == 0 && tid == 0) out[Bz*Nn*Nn + b] = *LL;
}

extern "C" void kernel_launch(void* const* d_in, const int* in_sizes, int n_in,
                              void* d_out, int out_size, void* d_ws, size_t ws_size,
                              hipStream_t stream)
{
  const float* z  = (const float*)d_in[0];
  const int*   tg = (const int*)  d_in[1];
  const float* Wi = (const float*)d_in[2];
  const float* bi = (const float*)d_in[3];
  const float* Wx = (const float*)d_in[4];
  const float* Wh = (const float*)d_in[5];
  const float* bx = (const float*)d_in[6];
  const float* bh = (const float*)d_in[7];
  const float* W1 = (const float*)d_in[8];
  const float* b1 = (const float*)d_in[9];
  const float* W2 = (const float*)d_in[10];
  const float* b2 = (const float*)d_in[11];
  float* out = (float*)d_out;
  float* ws  = (float*)d_ws;

  hipFuncSetAttribute((const void*)decoder_main,
                      hipFuncAttributeMaxDynamicSharedMemorySize, SMEM_SZ);

  hipLaunchKernelGGL(prep_init, dim3(512), dim3(256), 0, stream, tg, Wx, Wh, W1, ws, out);
  hipLaunchKernelGGL(prep_batch, dim3(Bz), dim3(256), 0, stream, z, Wi, bi, Wh, bh, W1, ws);

  void* args[] = { (void*)&tg, (void*)&bx, (void*)&bh, (void*)&b1,
                   (void*)&W2, (void*)&b2, (void*)&ws, (void*)&out };
  hipLaunchCooperativeKernel((void*)decoder_main, dim3(256), dim3(NT),
                             args, SMEM_SZ, stream);
}